// Round 3
// baseline (114.882 us; speedup 1.0000x reference)
//
#include <hip/hip_runtime.h>

#define BATCH 8192
#define NCOL  4096
#define NSLOT 256

// Zero-initialized at module load; the last-ticket block self-resets them
// every launch, so the all-zero invariant holds across graph replays.
__device__ double   g_slots[NSLOT];
__device__ unsigned g_count = 0;

// logaddexp with sentinel-safe identity: lae(-3e38, x) == x
__device__ __forceinline__ float lae(float a, float b) {
    float mx = fmaxf(a, b);
    float d  = fabsf(a - b);
    return mx + __logf(1.0f + __expf(-d));
}

__global__ __launch_bounds__(256) void listmle_fused(
        const float* __restrict__ outputs,
        const int*   __restrict__ labels,
        float*       __restrict__ out) {
    __shared__ float row[NCOL];     // staged outputs row (16 KB)
    __shared__ float wtot[4];       // per-wave scan totals (log domain)
    __shared__ float wsum[4];       // per-wave partial sums
    __shared__ double sh[4];        // last-block reduce scratch
    __shared__ unsigned lastFlag;

    const int t    = threadIdx.x;
    const int lane = t & 63;
    const int wid  = t >> 6;
    const size_t base = (size_t)blockIdx.x * NCOL;
    const float NEG = -3.0e38f;

    // ---- Phase 1: stage row into LDS, labels into registers ----
    const float4* o4 = (const float4*)(outputs + base);
    const int4*   l4 = (const int4*)(labels + base);
    float4* r4 = (float4*)row;

    float4 v[4];
#pragma unroll
    for (int k = 0; k < 4; ++k) v[k] = o4[k * 256 + t];
    int4 lb[4];
#pragma unroll
    for (int k = 0; k < 4; ++k) lb[k] = l4[4 * t + k];   // elems 16t..16t+15

    float sum_out = 0.f;
#pragma unroll
    for (int k = 0; k < 4; ++k) {
        r4[k * 256 + t] = v[k];
        sum_out += (v[k].x + v[k].y) + (v[k].z + v[k].w);
    }
    __syncthreads();

    // ---- Phase 2: gather own 16 elems; max-shifted exp prefix sums ----
    float g[16];
#pragma unroll
    for (int k = 0; k < 4; ++k) {
        g[4 * k + 0] = row[lb[k].x];
        g[4 * k + 1] = row[lb[k].y];
        g[4 * k + 2] = row[lb[k].z];
        g[4 * k + 3] = row[lb[k].w];
    }
    // chunk max (tree)
    float m01 = fmaxf(fmaxf(g[0], g[1]),  fmaxf(g[2], g[3]));
    float m23 = fmaxf(fmaxf(g[4], g[5]),  fmaxf(g[6], g[7]));
    float m45 = fmaxf(fmaxf(g[8], g[9]),  fmaxf(g[10], g[11]));
    float m67 = fmaxf(fmaxf(g[12], g[13]), fmaxf(g[14], g[15]));
    float m = fmaxf(fmaxf(m01, m23), fmaxf(m45, m67));

    // independent exps, cheap fadd prefix chain
    float s[16];
    float run = 0.f;
#pragma unroll
    for (int i = 0; i < 16; ++i) {
        run += __expf(g[i] - m);
        s[i] = run;
    }
    float T = m + __logf(run);   // chunk LSE (run >= 1, safe)

    // ---- Phase 3: wave inclusive lae-scan of chunk totals ----
    float p = T;
#pragma unroll
    for (int off = 1; off < 64; off <<= 1) {
        float o = __shfl_up(p, off, 64);
        if (lane >= off) p = lae(p, o);
    }
    if (lane == 63) wtot[wid] = p;      // wave total
    float ep = __shfl_up(p, 1, 64);     // exclusive lane prefix
    if (lane == 0) ep = NEG;
    __syncthreads();

    float wexc = NEG;                   // exclusive wave prefix
#pragma unroll
    for (int w = 0; w < 3; ++w)
        if (w < wid) wexc = lae(wexc, wtot[w]);
    float P = lae(wexc, ep);            // full exclusive prefix (log domain)

    // ---- Phase 4: sum of scores via single log of a product ----
    // score_j = m' + log(a + b*s_j);  sum_j score_j = 16*m' + log(prod_j c_j)
    float mp = fmaxf(P, m);
    float a  = __expf(P - mp);          // 0 when P is the -3e38 sentinel
    float b  = __expf(m - mp);
    float pr0 = 1.f, pr1 = 1.f;         // each <= 17^8 ~ 7e9; product < 5e19
#pragma unroll
    for (int i = 0; i < 16; i += 2) {
        pr0 *= fmaf(b, s[i],     a);
        pr1 *= fmaf(b, s[i + 1], a);
    }
    float ssum = 16.f * mp + __logf(pr0 * pr1);

    // ---- Phase 5: block reduction ----
    float part = ssum - sum_out;
#pragma unroll
    for (int off = 32; off; off >>= 1) part += __shfl_down(part, off, 64);
    if (lane == 0) wsum[wid] = part;
    __syncthreads();

    // ---- Phase 6: fence-free device accumulation + ticket ----
    if (t == 0) {
        double blockSum =
            (double)((wsum[0] + wsum[1]) + (wsum[2] + wsum[3]));
        // Device-scope RMW, performed at the coherent point. Using the
        // RETURNED value to feed the ticket forces the hardware to wait
        // for the slot-RMW response before the ticket RMW can issue —
        // release ordering with NO cache-flushing fence (round-1's
        // __threadfence L2-writeback poisoned co-running blocks' loads).
        double old = atomicAdd(&g_slots[blockIdx.x & (NSLOT - 1)], blockSum);
        unsigned z = (unsigned)__double_as_longlong(old);
        asm volatile("v_and_b32 %0, 0, %0" : "+v"(z));   // z = 0, dep kept
        unsigned prev = atomicAdd(&g_count, 1u + z);
        lastFlag = (prev == BATCH - 1u) ? 1u : 0u;
    }
    __syncthreads();

    // ---- Phase 7: last block finishes the reduction ----
    if (lastFlag) {                      // uniform across block
        // Coherent-point reads (atomic RMW of +0.0): every other block's
        // slot-add was performed at the coherent point BEFORE its ticket
        // increment, and we saw ticket == BATCH-1, so all are visible.
        double vsl = atomicAdd(&g_slots[t], 0.0);
#pragma unroll
        for (int off = 32; off; off >>= 1) vsl += __shfl_down(vsl, off, 64);
        if (lane == 0) sh[wid] = vsl;
        __syncthreads();
        if (t == 0) {
            double tot = (sh[0] + sh[1]) + (sh[2] + sh[3]);
            out[0] = (float)(tot * (1.0 / ((double)BATCH * (double)NCOL)));
            atomicExch(&g_count, 0u);    // reset ticket for next replay
        }
        // reset own slot for next replay (coherent store)
        atomicExch((unsigned long long*)&g_slots[t], 0ull);
    }
}

extern "C" void kernel_launch(void* const* d_in, const int* in_sizes, int n_in,
                              void* d_out, int out_size, void* d_ws, size_t ws_size,
                              hipStream_t stream) {
    const float* outputs = (const float*)d_in[0];
    const int*   labels  = (const int*)d_in[1];
    float* out = (float*)d_out;

    listmle_fused<<<BATCH, 256, 0, stream>>>(outputs, labels, out);
}

// Round 4
// 47.720 us; speedup vs baseline: 2.4074x; 2.4074x over previous
//
#include <hip/hip_runtime.h>

#define BATCH 8192
#define NCOL  4096
#define NSLOT 256

// Zero-initialized at module load. The reduce kernel self-resets them after
// every use, so the all-zero invariant holds across graph replays. No fences:
// kernel-boundary ordering provides cross-XCD visibility (same mechanism the
// proven two-kernel version relied on for its partial[] array).
//
// NOTE (rounds 1 & 3 post-mortem): do NOT fuse the final reduction into the
// main kernel. Both a __threadfence-based and a data-dependency-based
// last-block protocol regressed 2.4-6x: per-block device-scope RMW chains +
// the single-address ticket serialize at the coherent point and stall block
// retirement. The fire-and-forget atomicAdd below (result unused, 256
// addresses, <=32 contenders each) is proven free.
__device__ double g_slots[NSLOT];

// logaddexp with sentinel-safe identity: lae(-3e38, x) == x
__device__ __forceinline__ float lae(float a, float b) {
    float mx = fmaxf(a, b);
    float d  = fabsf(a - b);
    return mx + __logf(1.0f + __expf(-d));
}

__global__ __launch_bounds__(256) void listmle_main(
        const float* __restrict__ outputs,
        const int*   __restrict__ labels) {
    __shared__ float row[NCOL];     // staged outputs row (16 KB)
    __shared__ float wtot[4];       // per-wave scan totals (log domain)
    __shared__ float wsum[4];       // per-wave partial sums

    const int t    = threadIdx.x;
    const int lane = t & 63;
    const int wid  = t >> 6;
    const size_t base = (size_t)blockIdx.x * NCOL;
    const float NEG = -3.0e38f;

    // ---- Phase 1: stage row into LDS, labels into registers ----
    const float4* o4 = (const float4*)(outputs + base);
    const int4*   l4 = (const int4*)(labels + base);
    float4* r4 = (float4*)row;

    float4 v[4];
#pragma unroll
    for (int k = 0; k < 4; ++k) v[k] = o4[k * 256 + t];
    int4 lb[4];
#pragma unroll
    for (int k = 0; k < 4; ++k) lb[k] = l4[4 * t + k];   // elems 16t..16t+15

    float sum_out = 0.f;
#pragma unroll
    for (int k = 0; k < 4; ++k) {
        r4[k * 256 + t] = v[k];
        sum_out += (v[k].x + v[k].y) + (v[k].z + v[k].w);
    }
    __syncthreads();

    // ---- Phase 2: gather own 16 elems; max-shifted exp prefix sums ----
    float g[16];
#pragma unroll
    for (int k = 0; k < 4; ++k) {
        g[4 * k + 0] = row[lb[k].x];
        g[4 * k + 1] = row[lb[k].y];
        g[4 * k + 2] = row[lb[k].z];
        g[4 * k + 3] = row[lb[k].w];
    }
    // chunk max (tree)
    float m01 = fmaxf(fmaxf(g[0], g[1]),  fmaxf(g[2], g[3]));
    float m23 = fmaxf(fmaxf(g[4], g[5]),  fmaxf(g[6], g[7]));
    float m45 = fmaxf(fmaxf(g[8], g[9]),  fmaxf(g[10], g[11]));
    float m67 = fmaxf(fmaxf(g[12], g[13]), fmaxf(g[14], g[15]));
    float m = fmaxf(fmaxf(m01, m23), fmaxf(m45, m67));

    // independent exps, cheap fadd prefix chain
    float s[16];
    float run = 0.f;
#pragma unroll
    for (int i = 0; i < 16; ++i) {
        run += __expf(g[i] - m);
        s[i] = run;
    }
    float T = m + __logf(run);   // chunk LSE (run >= 1, safe)

    // ---- Phase 3: wave inclusive lae-scan of chunk totals ----
    float p = T;
#pragma unroll
    for (int off = 1; off < 64; off <<= 1) {
        float o = __shfl_up(p, off, 64);
        if (lane >= off) p = lae(p, o);
    }
    if (lane == 63) wtot[wid] = p;      // wave total
    float ep = __shfl_up(p, 1, 64);     // exclusive lane prefix
    if (lane == 0) ep = NEG;
    __syncthreads();

    float wexc = NEG;                   // exclusive wave prefix
#pragma unroll
    for (int w = 0; w < 3; ++w)
        if (w < wid) wexc = lae(wexc, wtot[w]);
    float P = lae(wexc, ep);            // full exclusive prefix (log domain)

    // ---- Phase 4: sum of scores via single log of a product ----
    // score_j = m' + log(a + b*s_j);  sum_j score_j = 16*m' + log(prod_j c_j)
    float mp = fmaxf(P, m);
    float a  = __expf(P - mp);          // 0 when P is the -3e38 sentinel
    float b  = __expf(m - mp);
    float pr0 = 1.f, pr1 = 1.f;         // each <= 17^8 ~ 7e9; product < 5e19
#pragma unroll
    for (int i = 0; i < 16; i += 2) {
        pr0 *= fmaf(b, s[i],     a);
        pr1 *= fmaf(b, s[i + 1], a);
    }
    float ssum = 16.f * mp + __logf(pr0 * pr1);

    // ---- Phase 5: block reduction, one atomic per block (NO fence) ----
    float part = ssum - sum_out;
#pragma unroll
    for (int off = 32; off; off >>= 1) part += __shfl_down(part, off, 64);
    if (lane == 0) wsum[wid] = part;
    __syncthreads();
    if (t == 0) {
        double blockSum =
            (double)((wsum[0] + wsum[1]) + (wsum[2] + wsum[3]));
        // 32 contenders per slot, result unused (fire-and-forget RMW).
        atomicAdd(&g_slots[blockIdx.x & (NSLOT - 1)], blockSum);
    }
}

__global__ __launch_bounds__(256) void listmle_reduce(float* __restrict__ out) {
    __shared__ double sh[4];
    const int t    = threadIdx.x;
    const int lane = t & 63;
    const int wid  = t >> 6;

    double s = g_slots[t];
    g_slots[t] = 0.0;                   // reset own slot for next replay
#pragma unroll
    for (int off = 32; off; off >>= 1) s += __shfl_down(s, off, 64);
    if (lane == 0) sh[wid] = s;
    __syncthreads();
    if (t == 0) {
        double tot = (sh[0] + sh[1]) + (sh[2] + sh[3]);
        out[0] = (float)(tot * (1.0 / ((double)BATCH * (double)NCOL)));
    }
}

extern "C" void kernel_launch(void* const* d_in, const int* in_sizes, int n_in,
                              void* d_out, int out_size, void* d_ws, size_t ws_size,
                              hipStream_t stream) {
    const float* outputs = (const float*)d_in[0];
    const int*   labels  = (const int*)d_in[1];
    float* out = (float*)d_out;

    listmle_main<<<BATCH, 256, 0, stream>>>(outputs, labels);
    listmle_reduce<<<1, 256, 0, stream>>>(out);
}